// Round 1
// baseline (5784.906 us; speedup 1.0000x reference)
//
#include <hip/hip_runtime.h>

// GraphSAGE 2-layer forward, fp32 correctness baseline.
// Pipeline: scatter-mean -> normalize -> GEMM(mean@Wl + x@Wr + b, relu)
//           -> scatter-mean(h) -> normalize -> GEMM -> out

#define N_NODES 50000
#define N_EDGES 800000

// ---------------- scatter-add (COO, one wave per edge) ----------------
__global__ __launch_bounds__(256) void scatter_accum(
    const float* __restrict__ feat, const int* __restrict__ ei,
    float* __restrict__ agg, float* __restrict__ cnt, int E, int D)
{
    int gid  = blockIdx.x * blockDim.x + threadIdx.x;
    int edge = gid >> 6;
    int lane = gid & 63;
    if (edge >= E) return;
    int s = ei[edge];        // row 0 of edge_index = src
    int d = ei[E + edge];    // row 1 = dst
    const float4* srow = (const float4*)(feat + (size_t)s * D);
    float* drow = agg + (size_t)d * D;
    int nv = D >> 2;
    for (int v = lane; v < nv; v += 64) {
        float4 val = srow[v];
        atomicAdd(drow + 4 * v + 0, val.x);
        atomicAdd(drow + 4 * v + 1, val.y);
        atomicAdd(drow + 4 * v + 2, val.z);
        atomicAdd(drow + 4 * v + 3, val.w);
    }
    if (cnt != nullptr && lane == 0) atomicAdd(cnt + d, 1.0f);
}

// ---------------- row normalize: agg[i,:] /= max(cnt[i],1) ----------------
__global__ __launch_bounds__(256) void normalize_rows(
    float* __restrict__ agg, const float* __restrict__ cnt, int M, int D)
{
    size_t i = (size_t)blockIdx.x * blockDim.x + threadIdx.x;
    if (i >= (size_t)M * D) return;
    int r = (int)(i / D);
    agg[i] = agg[i] / fmaxf(cnt[r], 1.0f);
}

// ---------------- fused dual GEMM: C = A0@B0 + A1@B1 + bias (opt relu) ----
// A0,A1: [M,K] row-major; B0,B1: [K,N] row-major; C: [M,N].
// BM=BN=64, BK=16, 256 threads, 4x4 acc per thread.
#define BM 64
#define BN 64
#define BK 16

__global__ __launch_bounds__(256) void sage_gemm(
    const float* __restrict__ A0, const float* __restrict__ A1,
    const float* __restrict__ B0, const float* __restrict__ B1,
    const float* __restrict__ bias, float* __restrict__ C,
    int M, int N, int K, int relu)
{
    // +2 pad on the BM dim kills the 16-way bank conflict on the staging store
    __shared__ float As[BK][BM + 2];
    __shared__ float Bs[BK][BN];

    int row0 = blockIdx.x * BM;
    int col0 = blockIdx.y * BN;
    int t  = threadIdx.x;
    int tx = t & 15;      // 0..15 -> 4 cols each
    int ty = t >> 4;      // 0..15 -> 4 rows each

    float acc[4][4] = {{0.f}};

    int ntiles = (2 * K) / BK;   // two A/B pairs stitched along K
    for (int kt = 0; kt < ntiles; ++kt) {
        int kBase = kt * BK;
        const float* A = A0;
        const float* B = B0;
        int kOff = kBase;
        if (kBase >= K) { A = A1; B = B1; kOff = kBase - K; }

        // A tile: 64 rows x 16 k  (1024 elems, 4/thread)
        #pragma unroll
        for (int i = 0; i < 4; ++i) {
            int l  = t + 256 * i;
            int r  = l >> 4;
            int kk = l & 15;
            int grow = row0 + r;
            float v = 0.f;
            if (grow < M) v = A[(size_t)grow * K + kOff + kk];
            As[kk][r] = v;
        }
        // B tile: 16 k x 64 n
        #pragma unroll
        for (int i = 0; i < 4; ++i) {
            int l  = t + 256 * i;
            int kk = l >> 6;
            int nn = l & 63;
            Bs[kk][nn] = B[(size_t)(kOff + kk) * N + col0 + nn];
        }
        __syncthreads();

        #pragma unroll
        for (int kk = 0; kk < BK; ++kk) {
            float a[4], b[4];
            #pragma unroll
            for (int i = 0; i < 4; ++i) a[i] = As[kk][ty * 4 + i];
            const float4 b4 = ((const float4*)Bs[kk])[tx];
            b[0] = b4.x; b[1] = b4.y; b[2] = b4.z; b[3] = b4.w;
            #pragma unroll
            for (int i = 0; i < 4; ++i)
                #pragma unroll
                for (int j = 0; j < 4; ++j)
                    acc[i][j] = fmaf(a[i], b[j], acc[i][j]);
        }
        __syncthreads();
    }

    #pragma unroll
    for (int i = 0; i < 4; ++i) {
        int grow = row0 + ty * 4 + i;
        if (grow >= M) continue;
        #pragma unroll
        for (int j = 0; j < 4; ++j) {
            int gcol = col0 + tx * 4 + j;
            float v = acc[i][j] + bias[gcol];
            if (relu) v = fmaxf(v, 0.f);
            C[(size_t)grow * N + gcol] = v;
        }
    }
}

extern "C" void kernel_launch(void* const* d_in, const int* in_sizes, int n_in,
                              void* d_out, int out_size, void* d_ws, size_t ws_size,
                              hipStream_t stream)
{
    const float* x   = (const float*)d_in[0];
    const int*   ei  = (const int*)d_in[1];   // [2, E] int32
    const float* W1l = (const float*)d_in[2];
    const float* b1  = (const float*)d_in[3];
    const float* W1r = (const float*)d_in[4];
    const float* W2l = (const float*)d_in[5];
    const float* b2  = (const float*)d_in[6];
    const float* W2r = (const float*)d_in[7];
    float* out = (float*)d_out;

    const int N = N_NODES, E = N_EDGES;
    const size_t cnt_bytes = 204800;                 // 50000 floats, padded
    const size_t agg_bytes = (size_t)N * 256 * 4;    // 51.2 MB

    char*  ws  = (char*)d_ws;
    float* cnt = (float*)ws;
    float* agg = (float*)(ws + cnt_bytes);
    float* h   = (float*)(ws + cnt_bytes + agg_bytes);

    if (ws_size < cnt_bytes + 2 * agg_bytes) return;  // workspace too small

    // ---- layer 1 ----
    hipMemsetAsync(ws, 0, cnt_bytes + agg_bytes, stream);   // cnt + agg = 0

    int sblocks = (E * 64) / 256;   // one wave per edge, 4 edges/block
    hipLaunchKernelGGL(scatter_accum, dim3(sblocks), dim3(256), 0, stream,
                       x, ei, agg, cnt, E, 256);
    hipLaunchKernelGGL(normalize_rows, dim3((N * 256) / 256), dim3(256), 0, stream,
                       agg, cnt, N, 256);
    hipLaunchKernelGGL(sage_gemm, dim3((N + BM - 1) / BM, 256 / BN), dim3(256), 0, stream,
                       agg, x, W1l, W1r, b1, h, N, 256, 256, 1);

    // ---- layer 2 ----
    hipMemsetAsync(agg, 0, agg_bytes, stream);
    hipLaunchKernelGGL(scatter_accum, dim3(sblocks), dim3(256), 0, stream,
                       h, ei, agg, (float*)nullptr, E, 256);
    hipLaunchKernelGGL(normalize_rows, dim3((N * 256) / 256), dim3(256), 0, stream,
                       agg, cnt, N, 256);
    hipLaunchKernelGGL(sage_gemm, dim3((N + BM - 1) / BM, 128 / BN), dim3(256), 0, stream,
                       agg, h, W2l, W2r, b2, out, N, 128, 256, 0);
}

// Round 2
// 649.094 us; speedup vs baseline: 8.9123x; 8.9123x over previous
//
#include <hip/hip_runtime.h>

// GraphSAGE 2-layer forward.
// Round 1: replace atomic scatter (2x2700us, atomic-bound) with CSR build +
// register-accumulating gather (no fp32 atomics). Layer 2 reordered via
// linearity: mean(h)@W2l == mean(h@W2l) -> gather on 128-wide rows, fused
// add into out = h@W2r + b2.

#define N_NODES 50000
#define N_EDGES 800000

// ---------------- CSR build ----------------
__global__ __launch_bounds__(256) void edge_hist(
    const int* __restrict__ ei, int* __restrict__ deg, int E)
{
    int e = blockIdx.x * blockDim.x + threadIdx.x;
    if (e < E) atomicAdd(&deg[ei[E + e]], 1);
}

#define SCAN_B 256
__global__ __launch_bounds__(256) void scan1(
    const int* __restrict__ deg, int* __restrict__ excl,
    int* __restrict__ bsum, int N)
{
    __shared__ int s[SCAN_B];
    int t = threadIdx.x;
    int i = blockIdx.x * SCAN_B + t;
    int v = (i < N) ? deg[i] : 0;
    s[t] = v;
    __syncthreads();
    for (int off = 1; off < SCAN_B; off <<= 1) {
        int add = (t >= off) ? s[t - off] : 0;
        __syncthreads();
        s[t] += add;
        __syncthreads();
    }
    if (i < N) excl[i] = s[t] - v;            // exclusive within block
    if (t == SCAN_B - 1) bsum[blockIdx.x] = s[t];
}

__global__ __launch_bounds__(256) void scan2(int* __restrict__ bsum, int nb)
{
    __shared__ int s[SCAN_B];
    int t = threadIdx.x;
    int v = (t < nb) ? bsum[t] : 0;
    s[t] = v;
    __syncthreads();
    for (int off = 1; off < SCAN_B; off <<= 1) {
        int add = (t >= off) ? s[t - off] : 0;
        __syncthreads();
        s[t] += add;
        __syncthreads();
    }
    if (t < nb) bsum[t] = s[t] - v;           // exclusive block offsets
}

__global__ __launch_bounds__(256) void scan3(
    int* __restrict__ rp, int* __restrict__ cursor,
    const int* __restrict__ bsum, int N, int E)
{
    int i = blockIdx.x * SCAN_B + threadIdx.x;
    if (i < N) {
        int v = rp[i] + bsum[blockIdx.x];
        rp[i] = v;
        cursor[i] = v;
    }
    if (i == 0) rp[N] = E;
}

__global__ __launch_bounds__(256) void edge_fill(
    const int* __restrict__ ei, int* __restrict__ cursor,
    int* __restrict__ col, int E)
{
    int e = blockIdx.x * blockDim.x + threadIdx.x;
    if (e >= E) return;
    int d = ei[E + e], s = ei[e];
    int pos = atomicAdd(&cursor[d], 1);
    col[pos] = s;
}

// ---------------- gather-mean: one wave per dst node ----------------
// D=256: lane holds float4; D=128: lane holds float2. ADD: out += mean.
template<int D, bool ADD>
__global__ __launch_bounds__(256) void gather_mean(
    const float* __restrict__ feat, const int* __restrict__ row_ptr,
    const int* __restrict__ col, float* __restrict__ outp, int N)
{
    constexpr int VPL = D / 64;   // floats per lane
    int gid  = blockIdx.x * blockDim.x + threadIdx.x;
    int node = gid >> 6;
    int lane = gid & 63;
    if (node >= N) return;
    int rs = row_ptr[node], re = row_ptr[node + 1];

    float acc[VPL];
    #pragma unroll
    for (int v = 0; v < VPL; ++v) acc[v] = 0.f;

    for (int base = rs; base < re; base += 64) {
        int m = re - base; if (m > 64) m = 64;
        int c = (lane < m) ? col[base + lane] : 0;
        for (int j = 0; j < m; ++j) {
            int src = __shfl(c, j);
            const float* srow = feat + (size_t)src * D + lane * VPL;
            if constexpr (VPL == 4) {
                float4 t = *(const float4*)srow;
                acc[0] += t.x; acc[1] += t.y; acc[2] += t.z; acc[3] += t.w;
            } else {
                float2 t = *(const float2*)srow;
                acc[0] += t.x; acc[1] += t.y;
            }
        }
    }

    float scale = 1.0f / (float)max(re - rs, 1);
    float* orow = outp + (size_t)node * D + lane * VPL;
    if constexpr (VPL == 4) {
        float4 o;
        if (ADD) {
            float4 p = *(const float4*)orow;
            o.x = p.x + acc[0] * scale; o.y = p.y + acc[1] * scale;
            o.z = p.z + acc[2] * scale; o.w = p.w + acc[3] * scale;
        } else {
            o.x = acc[0] * scale; o.y = acc[1] * scale;
            o.z = acc[2] * scale; o.w = acc[3] * scale;
        }
        *(float4*)orow = o;
    } else {
        float2 o;
        if (ADD) {
            float2 p = *(const float2*)orow;
            o.x = p.x + acc[0] * scale; o.y = p.y + acc[1] * scale;
        } else {
            o.x = acc[0] * scale; o.y = acc[1] * scale;
        }
        *(float2*)orow = o;
    }
}

// ---------------- fused GEMM: C = A0@B0 [+ A1@B1] [+ bias] [relu] ----------
#define BM 64
#define BN 64
#define BK 16

__global__ __launch_bounds__(256) void sage_gemm(
    const float* __restrict__ A0, const float* __restrict__ A1,
    const float* __restrict__ B0, const float* __restrict__ B1,
    const float* __restrict__ bias, float* __restrict__ C,
    int M, int N, int K, int relu)
{
    __shared__ float As[BK][BM + 2];
    __shared__ float Bs[BK][BN];

    int row0 = blockIdx.x * BM;
    int col0 = blockIdx.y * BN;
    int t  = threadIdx.x;
    int tx = t & 15;
    int ty = t >> 4;

    float acc[4][4] = {{0.f}};

    int ntiles = ((A1 ? 2 : 1) * K) / BK;
    for (int kt = 0; kt < ntiles; ++kt) {
        int kBase = kt * BK;
        const float* A = A0;
        const float* B = B0;
        int kOff = kBase;
        if (kBase >= K) { A = A1; B = B1; kOff = kBase - K; }

        #pragma unroll
        for (int i = 0; i < 4; ++i) {
            int l  = t + 256 * i;
            int r  = l >> 4;
            int kk = l & 15;
            int grow = row0 + r;
            float v = 0.f;
            if (grow < M) v = A[(size_t)grow * K + kOff + kk];
            As[kk][r] = v;
        }
        #pragma unroll
        for (int i = 0; i < 4; ++i) {
            int l  = t + 256 * i;
            int kk = l >> 6;
            int nn = l & 63;
            Bs[kk][nn] = B[(size_t)(kOff + kk) * N + col0 + nn];
        }
        __syncthreads();

        #pragma unroll
        for (int kk = 0; kk < BK; ++kk) {
            float a[4], b[4];
            #pragma unroll
            for (int i = 0; i < 4; ++i) a[i] = As[kk][ty * 4 + i];
            const float4 b4 = ((const float4*)Bs[kk])[tx];
            b[0] = b4.x; b[1] = b4.y; b[2] = b4.z; b[3] = b4.w;
            #pragma unroll
            for (int i = 0; i < 4; ++i)
                #pragma unroll
                for (int j = 0; j < 4; ++j)
                    acc[i][j] = fmaf(a[i], b[j], acc[i][j]);
        }
        __syncthreads();
    }

    #pragma unroll
    for (int i = 0; i < 4; ++i) {
        int grow = row0 + ty * 4 + i;
        if (grow >= M) continue;
        #pragma unroll
        for (int j = 0; j < 4; ++j) {
            int gcol = col0 + tx * 4 + j;
            float v = acc[i][j] + (bias ? bias[gcol] : 0.f);
            if (relu) v = fmaxf(v, 0.f);
            C[(size_t)grow * N + gcol] = v;
        }
    }
}

extern "C" void kernel_launch(void* const* d_in, const int* in_sizes, int n_in,
                              void* d_out, int out_size, void* d_ws, size_t ws_size,
                              hipStream_t stream)
{
    const float* x   = (const float*)d_in[0];
    const int*   ei  = (const int*)d_in[1];   // [2, E] int32
    const float* W1l = (const float*)d_in[2];
    const float* b1  = (const float*)d_in[3];
    const float* W1r = (const float*)d_in[4];
    const float* W2l = (const float*)d_in[5];
    const float* b2  = (const float*)d_in[6];
    const float* W2r = (const float*)d_in[7];
    float* out = (float*)d_out;

    const int N = N_NODES, E = N_EDGES;

    // workspace layout (256B aligned)
    const size_t off_deg  = 0;                        // int[50000]
    const size_t off_rp   = 204800;                   // int[50001]
    const size_t off_cur  = 409600;                   // int[50000]
    const size_t off_bsum = 614400;                   // int[256]
    const size_t off_col  = 618496;                   // int[800000]
    const size_t off_agg  = 3818496;                  // float[50000*256], reused as hl
    const size_t off_h    = off_agg + (size_t)N * 256 * 4;
    const size_t required = off_h + (size_t)N * 256 * 4;   // ~106.3 MB
    if (ws_size < required) return;

    char* ws = (char*)d_ws;
    int*   deg    = (int*)(ws + off_deg);
    int*   rp     = (int*)(ws + off_rp);
    int*   cursor = (int*)(ws + off_cur);
    int*   bsum   = (int*)(ws + off_bsum);
    int*   col    = (int*)(ws + off_col);
    float* agg    = (float*)(ws + off_agg);
    float* hl     = agg;                              // reuse after layer-1 GEMM
    float* h      = (float*)(ws + off_h);

    const int eb = (E + 255) / 256;                   // 3125
    const int nb = (N + SCAN_B - 1) / SCAN_B;         // 196

    // ---- CSR build (shared by both layers) ----
    hipMemsetAsync(deg, 0, (size_t)N * 4, stream);
    hipLaunchKernelGGL(edge_hist, dim3(eb), dim3(256), 0, stream, ei, deg, E);
    hipLaunchKernelGGL(scan1, dim3(nb), dim3(SCAN_B), 0, stream, deg, rp, bsum, N);
    hipLaunchKernelGGL(scan2, dim3(1), dim3(SCAN_B), 0, stream, bsum, nb);
    hipLaunchKernelGGL(scan3, dim3(nb), dim3(SCAN_B), 0, stream, rp, cursor, bsum, N, E);
    hipLaunchKernelGGL(edge_fill, dim3(eb), dim3(256), 0, stream, ei, cursor, col, E);

    // ---- layer 1: agg = mean(x[src]) ; h = relu(agg@W1l + x@W1r + b1) ----
    hipLaunchKernelGGL((gather_mean<256, false>), dim3((N + 3) / 4), dim3(256), 0, stream,
                       x, rp, col, agg, N);
    hipLaunchKernelGGL(sage_gemm, dim3((N + BM - 1) / BM, 256 / BN), dim3(256), 0, stream,
                       agg, x, W1l, W1r, b1, h, N, 256, 256, 1);

    // ---- layer 2: hl = h@W2l ; out = h@W2r + b2 ; out += mean(hl[src]) ----
    hipLaunchKernelGGL(sage_gemm, dim3((N + BM - 1) / BM, 128 / BN), dim3(256), 0, stream,
                       h, (const float*)nullptr, W2l, (const float*)nullptr,
                       (const float*)nullptr, hl, N, 128, 256, 0);
    hipLaunchKernelGGL(sage_gemm, dim3((N + BM - 1) / BM, 128 / BN), dim3(256), 0, stream,
                       h, (const float*)nullptr, W2r, (const float*)nullptr,
                       b2, out, N, 128, 256, 0);
    hipLaunchKernelGGL((gather_mean<128, true>), dim3((N + 3) / 4), dim3(256), 0, stream,
                       hl, rp, col, out, N);
}

// Round 3
// 317.529 us; speedup vs baseline: 18.2185x; 2.0442x over previous
//
#include <hip/hip_runtime.h>

// GraphSAGE 2-layer forward.
// Round 3: bf16 MFMA GEMMs (m97-style 128x128 tile, BK=64, global_load_lds
// width-16, T2 XOR swizzle via pre-swizzled source + swizzled read).
// Layer-2's two GEMMs fused into one N=256 GEMM h@[W2l|W2r] with split
// epilogue. All node features carried as bf16 (halves gather traffic).

#define N_NODES 50000
#define N_EDGES 800000

typedef unsigned short ushort_t;
typedef __attribute__((ext_vector_type(8))) short short8v;   // 8 bf16 = 4 VGPR
typedef __attribute__((ext_vector_type(4))) float f32x4;

__device__ __forceinline__ float b2f(ushort_t u) {
    union { unsigned int i; float f; } v; v.i = (unsigned int)u << 16; return v.f;
}
__device__ __forceinline__ ushort_t f2b(float f) {
    union { float f; unsigned int i; } v; v.f = f;
    unsigned int r = 0x7fffu + ((v.i >> 16) & 1u);   // RNE
    return (ushort_t)((v.i + r) >> 16);
}

// CK-style direct global->LDS (16B per lane; dest is wave-uniform base,
// HW adds lane*16; global source is per-lane).
__device__ __forceinline__ void gload_lds16(const void* gsrc, void* ldsdst) {
    auto* l3 = reinterpret_cast<__attribute__((address_space(3))) unsigned int*>(
        reinterpret_cast<uintptr_t>(ldsdst));
    __builtin_amdgcn_global_load_lds(
        reinterpret_cast<const unsigned int*>(gsrc), l3, 16, 0, 0);
}

// ---------------- CSR build ----------------
__global__ __launch_bounds__(256) void edge_hist(
    const int* __restrict__ ei, int* __restrict__ deg, int E)
{
    int e = blockIdx.x * blockDim.x + threadIdx.x;
    if (e < E) atomicAdd(&deg[ei[E + e]], 1);
}

#define SCAN_B 256
__global__ __launch_bounds__(256) void scan1(
    const int* __restrict__ deg, int* __restrict__ excl,
    int* __restrict__ bsum, int N)
{
    __shared__ int s[SCAN_B];
    int t = threadIdx.x;
    int i = blockIdx.x * SCAN_B + t;
    int v = (i < N) ? deg[i] : 0;
    s[t] = v;
    __syncthreads();
    for (int off = 1; off < SCAN_B; off <<= 1) {
        int add = (t >= off) ? s[t - off] : 0;
        __syncthreads();
        s[t] += add;
        __syncthreads();
    }
    if (i < N) excl[i] = s[t] - v;
    if (t == SCAN_B - 1) bsum[blockIdx.x] = s[t];
}

__global__ __launch_bounds__(256) void scan2(int* __restrict__ bsum, int nb)
{
    __shared__ int s[SCAN_B];
    int t = threadIdx.x;
    int v = (t < nb) ? bsum[t] : 0;
    s[t] = v;
    __syncthreads();
    for (int off = 1; off < SCAN_B; off <<= 1) {
        int add = (t >= off) ? s[t - off] : 0;
        __syncthreads();
        s[t] += add;
        __syncthreads();
    }
    if (t < nb) bsum[t] = s[t] - v;
}

__global__ __launch_bounds__(256) void scan3(
    int* __restrict__ rp, int* __restrict__ cursor,
    const int* __restrict__ bsum, int N, int E)
{
    int i = blockIdx.x * SCAN_B + threadIdx.x;
    if (i < N) {
        int v = rp[i] + bsum[blockIdx.x];
        rp[i] = v;
        cursor[i] = v;
    }
    if (i == 0) rp[N] = E;
}

__global__ __launch_bounds__(256) void edge_fill(
    const int* __restrict__ ei, int* __restrict__ cursor,
    int* __restrict__ col, int E)
{
    int e = blockIdx.x * blockDim.x + threadIdx.x;
    if (e >= E) return;
    int d = ei[E + e], s = ei[e];
    int pos = atomicAdd(&cursor[d], 1);
    col[pos] = s;
}

// ---------------- casts ----------------
__global__ __launch_bounds__(256) void cast_f32_bf16(
    const float* __restrict__ in, ushort_t* __restrict__ out, int n4)
{
    int i = blockIdx.x * blockDim.x + threadIdx.x;
    int stride = gridDim.x * blockDim.x;
    for (; i < n4; i += stride) {
        float4 v = ((const float4*)in)[i];
        ushort4 o;
        o.x = f2b(v.x); o.y = f2b(v.y); o.z = f2b(v.z); o.w = f2b(v.w);
        ((ushort4*)out)[i] = o;
    }
}

// Bt1[256][512] = [W1l;W1r]^T ; Bt2[256][256] = [W2l|W2r]^T  (bf16)
__global__ __launch_bounds__(256) void build_bt(
    const float* __restrict__ W1l, const float* __restrict__ W1r,
    const float* __restrict__ W2l, const float* __restrict__ W2r,
    ushort_t* __restrict__ Bt1, ushort_t* __restrict__ Bt2)
{
    int i = blockIdx.x * 256 + threadIdx.x;
    if (i < 256 * 512) {
        int n = i >> 9, k = i & 511;
        float v = (k < 256) ? W1l[k * 256 + n] : W1r[(k - 256) * 256 + n];
        Bt1[i] = f2b(v);
    }
    int j = i - 256 * 512;
    if (j >= 0 && j < 256 * 256) {
        int n = j >> 8, k = j & 255;
        float v = (n < 128) ? W2l[k * 128 + n] : W2r[k * 128 + (n - 128)];
        Bt2[j] = f2b(v);
    }
}

// ---------------- gather-mean (bf16 features), one wave per node ----------
template<int D, bool ADD>
__global__ __launch_bounds__(256) void gather_mean_b(
    const ushort_t* __restrict__ feat, const int* __restrict__ row_ptr,
    const int* __restrict__ col, ushort_t* __restrict__ outb,
    float* __restrict__ outf, int N)
{
    constexpr int VPL = D / 64;   // bf16 per lane: 4 (D=256) or 2 (D=128)
    int gid  = blockIdx.x * blockDim.x + threadIdx.x;
    int node = gid >> 6;
    int lane = gid & 63;
    if (node >= N) return;
    int rs = row_ptr[node], re = row_ptr[node + 1];

    float acc[VPL];
    #pragma unroll
    for (int v = 0; v < VPL; ++v) acc[v] = 0.f;

    for (int base = rs; base < re; base += 64) {
        int m = re - base; if (m > 64) m = 64;
        int c = (lane < m) ? col[base + lane] : 0;
        for (int j = 0; j < m; ++j) {
            int src = __shfl(c, j);
            const ushort_t* srow = feat + (size_t)src * D + lane * VPL;
            if constexpr (VPL == 4) {
                ushort4 t = *(const ushort4*)srow;
                acc[0] += b2f(t.x); acc[1] += b2f(t.y);
                acc[2] += b2f(t.z); acc[3] += b2f(t.w);
            } else {
                ushort2 t = *(const ushort2*)srow;
                acc[0] += b2f(t.x); acc[1] += b2f(t.y);
            }
        }
    }

    float s = 1.0f / (float)max(re - rs, 1);
    if constexpr (ADD) {            // D=128: out f32 += mean
        float* orow = outf + (size_t)node * D + lane * VPL;
        float2 p = *(float2*)orow;
        p.x += acc[0] * s; p.y += acc[1] * s;
        *(float2*)orow = p;
    } else {                        // D=256: write bf16 mean
        ushort_t* orow = outb + (size_t)node * D + lane * VPL;
        ushort4 o;
        o.x = f2b(acc[0] * s); o.y = f2b(acc[1] * s);
        o.z = f2b(acc[2] * s); o.w = f2b(acc[3] * s);
        *(ushort4*)orow = o;
    }
}

// ---------------- bf16 MFMA GEMM ----------------
// C[M,256] = [A0|A1] @ Bt^T  (A row stride fixed 256; Bt is [256][KT*64]).
// Tile 128x128, BK=64, 4 waves, each wave 64x64 (4x4 frags of 16x16x32).
// Epilogue: col < split -> outb (bf16, +biasb, opt relu); else outf (f32, +biasf).
template<int KT>   // 8 (virtual K=512) or 4 (K=256)
__global__ __launch_bounds__(256) void gemm_mfma(
    const ushort_t* __restrict__ A0, const ushort_t* __restrict__ A1,
    const ushort_t* __restrict__ Bt,
    const float* __restrict__ biasb, const float* __restrict__ biasf,
    ushort_t* __restrict__ outb, int ldb,
    float* __restrict__ outf, int ldf,
    int split, int M, int relu)
{
    __shared__ ushort_t As[128][64];   // 16 KB, row = 128 B
    __shared__ ushort_t Bs[128][64];   // 16 KB, row (= out col) = 128 B

    const int t    = threadIdx.x;
    const int lane = t & 63;
    const int w    = t >> 6;
    const int wr   = w >> 1, wc = w & 1;
    const int row0 = blockIdx.x * 128;
    const int col0 = blockIdx.y * 128;
    const int LDBT = KT * 64;

    f32x4 acc[4][4] = {};

    for (int kt = 0; kt < KT; ++kt) {
        const int kOff = kt * 64;
        const ushort_t* baseA = A0; int kA = kOff;
        if (KT == 8 && kOff >= 256) { baseA = A1; kA = kOff - 256; }

        __syncthreads();   // prev-iter readers done before overwrite
        // stage A (4 rounds x 256 thr x 16 B), linear LDS dest,
        // inverse-XOR-swizzled global source (rule #21c)
        #pragma unroll
        for (int i = 0; i < 4; ++i) {
            int o    = (i * 256 + t) * 16;      // dest byte (linear)
            int row  = o >> 7;
            int kb   = (o & 127) ^ ((row & 7) << 4);
            int grow = row0 + row; if (grow >= M) grow = M - 1;
            gload_lds16(baseA + (size_t)grow * 256 + kA + (kb >> 1),
                        (char*)&As[0][0] + i * 4096 + w * 1024);
        }
        #pragma unroll
        for (int i = 0; i < 4; ++i) {
            int o   = (i * 256 + t) * 16;
            int row = o >> 7;
            int kb  = (o & 127) ^ ((row & 7) << 4);
            gload_lds16(Bt + (size_t)(col0 + row) * LDBT + kOff + (kb >> 1),
                        (char*)&Bs[0][0] + i * 4096 + w * 1024);
        }
        __syncthreads();   // staging drained (compiler emits vmcnt(0))

        #pragma unroll
        for (int ks = 0; ks < 2; ++ks) {
            short8v af[4], bg[4];
            #pragma unroll
            for (int mi = 0; mi < 4; ++mi) {
                int row = (wr << 6) + (mi << 4) + (lane & 15);
                int kb  = ((ks << 6) + ((lane >> 4) << 4)) ^ ((row & 7) << 4);
                af[mi] = *(const short8v*)((const char*)&As[0][0] + row * 128 + kb);
            }
            #pragma unroll
            for (int nj = 0; nj < 4; ++nj) {
                int row = (wc << 6) + (nj << 4) + (lane & 15);
                int kb  = ((ks << 6) + ((lane >> 4) << 4)) ^ ((row & 7) << 4);
                bg[nj] = *(const short8v*)((const char*)&Bs[0][0] + row * 128 + kb);
            }
            #pragma unroll
            for (int mi = 0; mi < 4; ++mi)
                #pragma unroll
                for (int nj = 0; nj < 4; ++nj)
                    acc[mi][nj] = __builtin_amdgcn_mfma_f32_16x16x32_bf16(
                        af[mi], bg[nj], acc[mi][nj], 0, 0, 0);
        }
    }

    // epilogue: C/D layout col=lane&15, row=(lane>>4)*4+r (m89/m91)
    #pragma unroll
    for (int mi = 0; mi < 4; ++mi) {
        #pragma unroll
        for (int nj = 0; nj < 4; ++nj) {
            int c = col0 + (wc << 6) + (nj << 4) + (lane & 15);
            #pragma unroll
            for (int r = 0; r < 4; ++r) {
                int row = row0 + (wr << 6) + (mi << 4) + ((lane >> 4) << 2) + r;
                if (row >= M) continue;
                float v = acc[mi][nj][r];
                if (c < split) {
                    if (biasb) v += biasb[c];
                    if (relu)  v = fmaxf(v, 0.f);
                    outb[(size_t)row * ldb + c] = f2b(v);
                } else {
                    if (biasf) v += biasf[c - split];
                    outf[(size_t)row * ldf + (c - split)] = v;
                }
            }
        }
    }
}

extern "C" void kernel_launch(void* const* d_in, const int* in_sizes, int n_in,
                              void* d_out, int out_size, void* d_ws, size_t ws_size,
                              hipStream_t stream)
{
    const float* x   = (const float*)d_in[0];
    const int*   ei  = (const int*)d_in[1];
    const float* W1l = (const float*)d_in[2];
    const float* b1  = (const float*)d_in[3];
    const float* W1r = (const float*)d_in[4];
    const float* W2l = (const float*)d_in[5];
    const float* b2  = (const float*)d_in[6];
    const float* W2r = (const float*)d_in[7];
    float* out = (float*)d_out;

    const int N = N_NODES, E = N_EDGES;

    // workspace layout (256 B aligned)
    const size_t off_deg  = 0;
    const size_t off_rp   = 204800;
    const size_t off_cur  = 409600;
    const size_t off_bsum = 614400;
    const size_t off_col  = 615424;
    const size_t off_xb   = 3815424;                         // bf16 [N][256]
    const size_t off_aggb = off_xb   + (size_t)N * 256 * 2;  // bf16 [N][256]
    const size_t off_h    = off_aggb + (size_t)N * 256 * 2;  // bf16 [N][256]
    const size_t off_hl   = off_h    + (size_t)N * 256 * 2;  // bf16 [N][128]
    const size_t off_bt1  = off_hl   + (size_t)N * 128 * 2;
    const size_t off_bt2  = off_bt1  + 256 * 512 * 2;
    const size_t required = off_bt2  + 256 * 256 * 2;        // ~93.8 MB
    if (ws_size < required) return;

    char* ws = (char*)d_ws;
    int*      deg    = (int*)(ws + off_deg);
    int*      rp     = (int*)(ws + off_rp);
    int*      cursor = (int*)(ws + off_cur);
    int*      bsum   = (int*)(ws + off_bsum);
    int*      col    = (int*)(ws + off_col);
    ushort_t* xb     = (ushort_t*)(ws + off_xb);
    ushort_t* aggb   = (ushort_t*)(ws + off_aggb);
    ushort_t* h      = (ushort_t*)(ws + off_h);
    ushort_t* hl     = (ushort_t*)(ws + off_hl);
    ushort_t* Bt1    = (ushort_t*)(ws + off_bt1);
    ushort_t* Bt2    = (ushort_t*)(ws + off_bt2);

    const int eb = (E + 255) / 256;
    const int nb = (N + SCAN_B - 1) / SCAN_B;
    const int mt = (N + 127) / 128;   // 391 M-tiles

    // ---- CSR build ----
    hipMemsetAsync(deg, 0, (size_t)N * 4, stream);
    hipLaunchKernelGGL(edge_hist, dim3(eb), dim3(256), 0, stream, ei, deg, E);
    hipLaunchKernelGGL(scan1, dim3(nb), dim3(SCAN_B), 0, stream, deg, rp, bsum, N);
    hipLaunchKernelGGL(scan2, dim3(1), dim3(SCAN_B), 0, stream, bsum, nb);
    hipLaunchKernelGGL(scan3, dim3(nb), dim3(SCAN_B), 0, stream, rp, cursor, bsum, N, E);
    hipLaunchKernelGGL(edge_fill, dim3(eb), dim3(256), 0, stream, ei, cursor, col, E);

    // ---- casts ----
    hipLaunchKernelGGL(cast_f32_bf16, dim3(2048), dim3(256), 0, stream,
                       x, xb, N * 256 / 4);
    hipLaunchKernelGGL(build_bt, dim3(768), dim3(256), 0, stream,
                       W1l, W1r, W2l, W2r, Bt1, Bt2);

    // ---- layer 1: aggb = mean(xb[src]); h = relu([aggb|xb]@[W1l;W1r] + b1) ----
    hipLaunchKernelGGL((gather_mean_b<256, false>), dim3((N + 3) / 4), dim3(256), 0, stream,
                       xb, rp, col, aggb, (float*)nullptr, N);
    hipLaunchKernelGGL((gemm_mfma<8>), dim3(mt, 2), dim3(256), 0, stream,
                       aggb, xb, Bt1, b1, (const float*)nullptr,
                       h, 256, (float*)nullptr, 0, 256, N, 1);

    // ---- layer 2: [hl|out] = h@[W2l|W2r] (+b2 on out); out += mean(hl[src]) ----
    hipLaunchKernelGGL((gemm_mfma<4>), dim3(mt, 2), dim3(256), 0, stream,
                       h, (const ushort_t*)nullptr, Bt2,
                       (const float*)nullptr, b2,
                       hl, 128, out, 128, 128, N, 0);
    hipLaunchKernelGGL((gather_mean_b<128, true>), dim3((N + 3) / 4), dim3(256), 0, stream,
                       hl, rp, col, (ushort_t*)nullptr, out, N);
}

// Round 4
// 275.114 us; speedup vs baseline: 21.0273x; 1.1542x over previous
//
#include <hip/hip_runtime.h>

// GraphSAGE 2-layer forward.
// Round 4: GEMM gets double-buffered LDS + counted vmcnt(8) (T3/T4 minimum
// 2-phase recipe) -- loads stay in flight across barriers, no vmcnt(0) drain
// in the K-loop. Gather inner loop hand-unrolled 4-wide for load ILP.

#define N_NODES 50000
#define N_EDGES 800000

typedef unsigned short ushort_t;
typedef __attribute__((ext_vector_type(8))) short short8v;   // 8 bf16 = 4 VGPR
typedef __attribute__((ext_vector_type(4))) float f32x4;

__device__ __forceinline__ float b2f(ushort_t u) {
    union { unsigned int i; float f; } v; v.i = (unsigned int)u << 16; return v.f;
}
__device__ __forceinline__ ushort_t f2b(float f) {
    union { float f; unsigned int i; } v; v.f = f;
    unsigned int r = 0x7fffu + ((v.i >> 16) & 1u);   // RNE
    return (ushort_t)((v.i + r) >> 16);
}

__device__ __forceinline__ void gload_lds16(const void* gsrc, void* ldsdst) {
    auto* l3 = reinterpret_cast<__attribute__((address_space(3))) unsigned int*>(
        reinterpret_cast<uintptr_t>(ldsdst));
    __builtin_amdgcn_global_load_lds(
        reinterpret_cast<const unsigned int*>(gsrc), l3, 16, 0, 0);
}

// ---------------- CSR build ----------------
__global__ __launch_bounds__(256) void edge_hist(
    const int* __restrict__ ei, int* __restrict__ deg, int E)
{
    int e = blockIdx.x * blockDim.x + threadIdx.x;
    if (e < E) atomicAdd(&deg[ei[E + e]], 1);
}

#define SCAN_B 256
__global__ __launch_bounds__(256) void scan1(
    const int* __restrict__ deg, int* __restrict__ excl,
    int* __restrict__ bsum, int N)
{
    __shared__ int s[SCAN_B];
    int t = threadIdx.x;
    int i = blockIdx.x * SCAN_B + t;
    int v = (i < N) ? deg[i] : 0;
    s[t] = v;
    __syncthreads();
    for (int off = 1; off < SCAN_B; off <<= 1) {
        int add = (t >= off) ? s[t - off] : 0;
        __syncthreads();
        s[t] += add;
        __syncthreads();
    }
    if (i < N) excl[i] = s[t] - v;
    if (t == SCAN_B - 1) bsum[blockIdx.x] = s[t];
}

__global__ __launch_bounds__(256) void scan2(int* __restrict__ bsum, int nb)
{
    __shared__ int s[SCAN_B];
    int t = threadIdx.x;
    int v = (t < nb) ? bsum[t] : 0;
    s[t] = v;
    __syncthreads();
    for (int off = 1; off < SCAN_B; off <<= 1) {
        int add = (t >= off) ? s[t - off] : 0;
        __syncthreads();
        s[t] += add;
        __syncthreads();
    }
    if (t < nb) bsum[t] = s[t] - v;
}

__global__ __launch_bounds__(256) void scan3(
    int* __restrict__ rp, int* __restrict__ cursor,
    const int* __restrict__ bsum, int N, int E)
{
    int i = blockIdx.x * SCAN_B + threadIdx.x;
    if (i < N) {
        int v = rp[i] + bsum[blockIdx.x];
        rp[i] = v;
        cursor[i] = v;
    }
    if (i == 0) rp[N] = E;
}

__global__ __launch_bounds__(256) void edge_fill(
    const int* __restrict__ ei, int* __restrict__ cursor,
    int* __restrict__ col, int E)
{
    int e = blockIdx.x * blockDim.x + threadIdx.x;
    if (e >= E) return;
    int d = ei[E + e], s = ei[e];
    int pos = atomicAdd(&cursor[d], 1);
    col[pos] = s;
}

// ---------------- casts ----------------
__global__ __launch_bounds__(256) void cast_f32_bf16(
    const float* __restrict__ in, ushort_t* __restrict__ out, int n4)
{
    int i = blockIdx.x * blockDim.x + threadIdx.x;
    int stride = gridDim.x * blockDim.x;
    for (; i < n4; i += stride) {
        float4 v = ((const float4*)in)[i];
        ushort4 o;
        o.x = f2b(v.x); o.y = f2b(v.y); o.z = f2b(v.z); o.w = f2b(v.w);
        ((ushort4*)out)[i] = o;
    }
}

// Bt1[256][512] = [W1l;W1r]^T ; Bt2[256][256] = [W2l|W2r]^T  (bf16)
__global__ __launch_bounds__(256) void build_bt(
    const float* __restrict__ W1l, const float* __restrict__ W1r,
    const float* __restrict__ W2l, const float* __restrict__ W2r,
    ushort_t* __restrict__ Bt1, ushort_t* __restrict__ Bt2)
{
    int i = blockIdx.x * 256 + threadIdx.x;
    if (i < 256 * 512) {
        int n = i >> 9, k = i & 511;
        float v = (k < 256) ? W1l[k * 256 + n] : W1r[(k - 256) * 256 + n];
        Bt1[i] = f2b(v);
    }
    int j = i - 256 * 512;
    if (j >= 0 && j < 256 * 256) {
        int n = j >> 8, k = j & 255;
        float v = (n < 128) ? W2l[k * 128 + n] : W2r[k * 128 + (n - 128)];
        Bt2[j] = f2b(v);
    }
}

// ---------------- gather-mean (bf16 features), one wave per node ----------
template<int D, bool ADD>
__global__ __launch_bounds__(256) void gather_mean_b(
    const ushort_t* __restrict__ feat, const int* __restrict__ row_ptr,
    const int* __restrict__ col, ushort_t* __restrict__ outb,
    float* __restrict__ outf, int N)
{
    constexpr int VPL = D / 64;   // bf16 per lane: 4 (D=256) or 2 (D=128)
    int gid  = blockIdx.x * blockDim.x + threadIdx.x;
    int node = gid >> 6;
    int lane = gid & 63;
    if (node >= N) return;
    int rs = row_ptr[node], re = row_ptr[node + 1];

    float acc[VPL];
    #pragma unroll
    for (int v = 0; v < VPL; ++v) acc[v] = 0.f;

    for (int base = rs; base < re; base += 64) {
        int m = re - base; if (m > 64) m = 64;
        int c = (lane < m) ? col[base + lane] : 0;
        int j = 0;
        // 4-wide: issue 4 independent row loads before accumulating
        for (; j + 4 <= m; j += 4) {
            int s0 = __shfl(c, j);
            int s1 = __shfl(c, j + 1);
            int s2 = __shfl(c, j + 2);
            int s3 = __shfl(c, j + 3);
            if constexpr (VPL == 4) {
                ushort4 t0 = *(const ushort4*)(feat + (size_t)s0 * D + lane * 4);
                ushort4 t1 = *(const ushort4*)(feat + (size_t)s1 * D + lane * 4);
                ushort4 t2 = *(const ushort4*)(feat + (size_t)s2 * D + lane * 4);
                ushort4 t3 = *(const ushort4*)(feat + (size_t)s3 * D + lane * 4);
                acc[0] += b2f(t0.x) + b2f(t1.x) + b2f(t2.x) + b2f(t3.x);
                acc[1] += b2f(t0.y) + b2f(t1.y) + b2f(t2.y) + b2f(t3.y);
                acc[2] += b2f(t0.z) + b2f(t1.z) + b2f(t2.z) + b2f(t3.z);
                acc[3] += b2f(t0.w) + b2f(t1.w) + b2f(t2.w) + b2f(t3.w);
            } else {
                ushort2 t0 = *(const ushort2*)(feat + (size_t)s0 * D + lane * 2);
                ushort2 t1 = *(const ushort2*)(feat + (size_t)s1 * D + lane * 2);
                ushort2 t2 = *(const ushort2*)(feat + (size_t)s2 * D + lane * 2);
                ushort2 t3 = *(const ushort2*)(feat + (size_t)s3 * D + lane * 2);
                acc[0] += b2f(t0.x) + b2f(t1.x) + b2f(t2.x) + b2f(t3.x);
                acc[1] += b2f(t0.y) + b2f(t1.y) + b2f(t2.y) + b2f(t3.y);
            }
        }
        for (; j < m; ++j) {
            int src = __shfl(c, j);
            if constexpr (VPL == 4) {
                ushort4 t = *(const ushort4*)(feat + (size_t)src * D + lane * 4);
                acc[0] += b2f(t.x); acc[1] += b2f(t.y);
                acc[2] += b2f(t.z); acc[3] += b2f(t.w);
            } else {
                ushort2 t = *(const ushort2*)(feat + (size_t)src * D + lane * 2);
                acc[0] += b2f(t.x); acc[1] += b2f(t.y);
            }
        }
    }

    float s = 1.0f / (float)max(re - rs, 1);
    if constexpr (ADD) {            // D=128: out f32 += mean
        float* orow = outf + (size_t)node * D + lane * VPL;
        float2 p = *(float2*)orow;
        p.x += acc[0] * s; p.y += acc[1] * s;
        *(float2*)orow = p;
    } else {                        // D=256: write bf16 mean
        ushort_t* orow = outb + (size_t)node * D + lane * VPL;
        ushort4 o;
        o.x = f2b(acc[0] * s); o.y = f2b(acc[1] * s);
        o.z = f2b(acc[2] * s); o.w = f2b(acc[3] * s);
        *(ushort4*)orow = o;
    }
}

// ---------------- bf16 MFMA GEMM, double-buffered + counted vmcnt ----------
// C[M,256] = [A0|A1] @ Bt^T. Tile 128x128, BK=64, 4 waves x (64x64 out).
// Per wave per stage: 8 global_load_lds (16B). Steady state: 16 in flight,
// vmcnt(8) waits only for the CURRENT tile -- prefetch spans both barriers.
template<int KT>   // 8 (virtual K=512) or 4 (K=256)
__global__ __launch_bounds__(256) void gemm_mfma(
    const ushort_t* __restrict__ A0, const ushort_t* __restrict__ A1,
    const ushort_t* __restrict__ Bt,
    const float* __restrict__ biasb, const float* __restrict__ biasf,
    ushort_t* __restrict__ outb, int ldb,
    float* __restrict__ outf, int ldf,
    int split, int M, int relu)
{
    __shared__ ushort_t As[2][128][64];   // 2 x 16 KB
    __shared__ ushort_t Bs[2][128][64];   // 2 x 16 KB

    const int t    = threadIdx.x;
    const int lane = t & 63;
    const int w    = t >> 6;
    const int wr   = w >> 1, wc = w & 1;
    const int row0 = blockIdx.x * 128;
    const int col0 = blockIdx.y * 128;
    const int LDBT = KT * 64;

    f32x4 acc[4][4] = {};

    auto stage = [&](int kt, int buf) {
        const int kOff = kt * 64;
        const ushort_t* baseA = A0; int kA = kOff;
        if (KT == 8 && kOff >= 256) { baseA = A1; kA = kOff - 256; }
        #pragma unroll
        for (int i = 0; i < 4; ++i) {
            int o    = (i * 256 + t) * 16;            // linear dest byte
            int row  = o >> 7;
            int kb   = (o & 127) ^ ((row & 7) << 4);  // inverse-swizzled source
            int grow = row0 + row; if (grow >= M) grow = M - 1;
            gload_lds16(baseA + (size_t)grow * 256 + kA + (kb >> 1),
                        (char*)&As[buf][0][0] + i * 4096 + w * 1024);
        }
        #pragma unroll
        for (int i = 0; i < 4; ++i) {
            int o   = (i * 256 + t) * 16;
            int row = o >> 7;
            int kb  = (o & 127) ^ ((row & 7) << 4);
            gload_lds16(Bt + (size_t)(col0 + row) * LDBT + kOff + (kb >> 1),
                        (char*)&Bs[buf][0][0] + i * 4096 + w * 1024);
        }
    };

    stage(0, 0);
    for (int kt = 0; kt < KT; ++kt) {
        const int buf = kt & 1;
        if (kt + 1 < KT) {
            stage(kt + 1, buf ^ 1);                   // prefetch next tile
            asm volatile("s_waitcnt vmcnt(8)");       // wait CURRENT tile only
        } else {
            asm volatile("s_waitcnt vmcnt(0)");
        }
        __builtin_amdgcn_sched_barrier(0);
        __builtin_amdgcn_s_barrier();                  // all waves staged
        __builtin_amdgcn_sched_barrier(0);

        #pragma unroll
        for (int ks = 0; ks < 2; ++ks) {
            short8v af[4], bg[4];
            #pragma unroll
            for (int mi = 0; mi < 4; ++mi) {
                int row = (wr << 6) + (mi << 4) + (lane & 15);
                int kb  = ((ks << 6) + ((lane >> 4) << 4)) ^ ((row & 7) << 4);
                af[mi] = *(const short8v*)((const char*)&As[buf][0][0] + row * 128 + kb);
            }
            #pragma unroll
            for (int nj = 0; nj < 4; ++nj) {
                int row = (wc << 6) + (nj << 4) + (lane & 15);
                int kb  = ((ks << 6) + ((lane >> 4) << 4)) ^ ((row & 7) << 4);
                bg[nj] = *(const short8v*)((const char*)&Bs[buf][0][0] + row * 128 + kb);
            }
            #pragma unroll
            for (int mi = 0; mi < 4; ++mi)
                #pragma unroll
                for (int nj = 0; nj < 4; ++nj)
                    acc[mi][nj] = __builtin_amdgcn_mfma_f32_16x16x32_bf16(
                        af[mi], bg[nj], acc[mi][nj], 0, 0, 0);
        }

        __builtin_amdgcn_sched_barrier(0);
        __builtin_amdgcn_s_barrier();                  // release buf for kt+2
        __builtin_amdgcn_sched_barrier(0);
    }

    // epilogue: C/D layout col=lane&15, row=(lane>>4)*4+r (m89/m91)
    #pragma unroll
    for (int mi = 0; mi < 4; ++mi) {
        #pragma unroll
        for (int nj = 0; nj < 4; ++nj) {
            int c = col0 + (wc << 6) + (nj << 4) + (lane & 15);
            #pragma unroll
            for (int r = 0; r < 4; ++r) {
                int row = row0 + (wr << 6) + (mi << 4) + ((lane >> 4) << 2) + r;
                if (row >= M) continue;
                float v = acc[mi][nj][r];
                if (c < split) {
                    if (biasb) v += biasb[c];
                    if (relu)  v = fmaxf(v, 0.f);
                    outb[(size_t)row * ldb + c] = f2b(v);
                } else {
                    if (biasf) v += biasf[c - split];
                    outf[(size_t)row * ldf + (c - split)] = v;
                }
            }
        }
    }
}

extern "C" void kernel_launch(void* const* d_in, const int* in_sizes, int n_in,
                              void* d_out, int out_size, void* d_ws, size_t ws_size,
                              hipStream_t stream)
{
    const float* x   = (const float*)d_in[0];
    const int*   ei  = (const int*)d_in[1];
    const float* W1l = (const float*)d_in[2];
    const float* b1  = (const float*)d_in[3];
    const float* W1r = (const float*)d_in[4];
    const float* W2l = (const float*)d_in[5];
    const float* b2  = (const float*)d_in[6];
    const float* W2r = (const float*)d_in[7];
    float* out = (float*)d_out;

    const int N = N_NODES, E = N_EDGES;

    // workspace layout (256 B aligned)
    const size_t off_deg  = 0;
    const size_t off_rp   = 204800;
    const size_t off_cur  = 409600;
    const size_t off_bsum = 614400;
    const size_t off_col  = 615424;
    const size_t off_xb   = 3815424;                         // bf16 [N][256]
    const size_t off_aggb = off_xb   + (size_t)N * 256 * 2;  // bf16 [N][256]
    const size_t off_h    = off_aggb + (size_t)N * 256 * 2;  // bf16 [N][256]
    const size_t off_hl   = off_h    + (size_t)N * 256 * 2;  // bf16 [N][128]
    const size_t off_bt1  = off_hl   + (size_t)N * 128 * 2;
    const size_t off_bt2  = off_bt1  + 256 * 512 * 2;
    const size_t required = off_bt2  + 256 * 256 * 2;        // ~93.8 MB
    if (ws_size < required) return;

    char* ws = (char*)d_ws;
    int*      deg    = (int*)(ws + off_deg);
    int*      rp     = (int*)(ws + off_rp);
    int*      cursor = (int*)(ws + off_cur);
    int*      bsum   = (int*)(ws + off_bsum);
    int*      col    = (int*)(ws + off_col);
    ushort_t* xb     = (ushort_t*)(ws + off_xb);
    ushort_t* aggb   = (ushort_t*)(ws + off_aggb);
    ushort_t* h      = (ushort_t*)(ws + off_h);
    ushort_t* hl     = (ushort_t*)(ws + off_hl);
    ushort_t* Bt1    = (ushort_t*)(ws + off_bt1);
    ushort_t* Bt2    = (ushort_t*)(ws + off_bt2);

    const int eb = (E + 255) / 256;
    const int nb = (N + SCAN_B - 1) / SCAN_B;
    const int mt = (N + 127) / 128;   // 391 M-tiles

    // ---- CSR build ----
    hipMemsetAsync(deg, 0, (size_t)N * 4, stream);
    hipLaunchKernelGGL(edge_hist, dim3(eb), dim3(256), 0, stream, ei, deg, E);
    hipLaunchKernelGGL(scan1, dim3(nb), dim3(SCAN_B), 0, stream, deg, rp, bsum, N);
    hipLaunchKernelGGL(scan2, dim3(1), dim3(SCAN_B), 0, stream, bsum, nb);
    hipLaunchKernelGGL(scan3, dim3(nb), dim3(SCAN_B), 0, stream, rp, cursor, bsum, N, E);
    hipLaunchKernelGGL(edge_fill, dim3(eb), dim3(256), 0, stream, ei, cursor, col, E);

    // ---- casts ----
    hipLaunchKernelGGL(cast_f32_bf16, dim3(2048), dim3(256), 0, stream,
                       x, xb, N * 256 / 4);
    hipLaunchKernelGGL(build_bt, dim3(768), dim3(256), 0, stream,
                       W1l, W1r, W2l, W2r, Bt1, Bt2);

    // ---- layer 1: aggb = mean(xb[src]); h = relu([aggb|xb]@[W1l;W1r] + b1) ----
    hipLaunchKernelGGL((gather_mean_b<256, false>), dim3((N + 3) / 4), dim3(256), 0, stream,
                       xb, rp, col, aggb, (float*)nullptr, N);
    hipLaunchKernelGGL((gemm_mfma<8>), dim3(mt, 2), dim3(256), 0, stream,
                       aggb, xb, Bt1, b1, (const float*)nullptr,
                       h, 256, (float*)nullptr, 0, 256, N, 1);

    // ---- layer 2: [hl|out] = h@[W2l|W2r] (+b2 on out); out += mean(hl[src]) ----
    hipLaunchKernelGGL((gemm_mfma<4>), dim3(mt, 2), dim3(256), 0, stream,
                       h, (const ushort_t*)nullptr, Bt2,
                       (const float*)nullptr, b2,
                       hl, 128, out, 128, 128, N, 0);
    hipLaunchKernelGGL((gather_mean_b<128, true>), dim3((N + 3) / 4), dim3(256), 0, stream,
                       hl, rp, col, (ushort_t*)nullptr, out, N);
}